// Round 12
// baseline (299.697 us; speedup 1.0000x reference)
//
#include <hip/hip_runtime.h>

#define N_NODES 50000
#define N_EDGES 1600000
#define IN_F 256
#define H1_F 128
#define H2_F 64
#define OUT_F 2
#define BN_EPS 1e-5f

#define NBUK 782          // ceil(50000/64) buckets of 64 nodes
#define BCAP 3584         // LDS edge capacity per bucket in build (avg 2048)
#define CHUNK 4096        // edges per chunk
#define NCHUNK 391        // ceil(1600000/4096)
#define NPW 8             // nodes per wave in aggregation (50000 % 8 == 0)

typedef __attribute__((ext_vector_type(8))) short bf16x8;   // 8 bf16 in 4 VGPRs
typedef __attribute__((ext_vector_type(4))) float f32x4;
typedef __attribute__((ext_vector_type(4))) int   i32x4;
typedef __attribute__((ext_vector_type(4))) unsigned u32x4;

// ---------------------------------------------------------------- bf16 helpers
__device__ __forceinline__ unsigned short f2b(float f) {
    union { float f; unsigned u; } v; v.f = f;
    unsigned r = (v.u + 0x7FFFu + ((v.u >> 16) & 1u)) >> 16;
    return (unsigned short)r;
}
__device__ __forceinline__ float b2f(unsigned short b) {
    union { unsigned u; float f; } v; v.u = ((unsigned)b) << 16;
    return v.f;
}
__device__ __forceinline__ void add2(float& a0, float& a1, unsigned u) {
    union { unsigned u; float f; } lo, hi;
    lo.u = u << 16;
    hi.u = u & 0xFFFF0000u;
    a0 += lo.f; a1 += hi.f;
}

// ---------------------------------------------------------------- pass A: per-chunk bucket histogram (bucket-major h)
__launch_bounds__(256)
__global__ void chist_kernel(const int* __restrict__ dst, int* __restrict__ h,
                             int* __restrict__ tot) {
    __shared__ int lh[NBUK];
    const int c = blockIdx.x;
    for (int i = threadIdx.x; i < NBUK; i += 256) lh[i] = 0;
    __syncthreads();
    const int e0 = c * CHUNK;
    const int e1 = min(e0 + CHUNK, N_EDGES);
    const i32x4* p = (const i32x4*)(dst + e0);
    const int n4 = (e1 - e0) >> 2;
    for (int i = threadIdx.x; i < n4; i += 256) {
        i32x4 d = __builtin_nontemporal_load(p + i);
        atomicAdd(&lh[d.x >> 6], 1);
        atomicAdd(&lh[d.y >> 6], 1);
        atomicAdd(&lh[d.z >> 6], 1);
        atomicAdd(&lh[d.w >> 6], 1);
    }
    __syncthreads();
    for (int i = threadIdx.x; i < NBUK; i += 256) {
        int v = lh[i];
        h[(size_t)i * NCHUNK + c] = v;
        if (v) atomicAdd(&tot[i], v);      // fire-and-forget
    }
}

// ---------------------------------------------------------------- pass B1: scan 782 bucket totals (1 block)
__global__ void bscan_kernel(const int* __restrict__ tot, int* __restrict__ boff,
                             int* __restrict__ rowptr) {
    __shared__ int tmp[1024];
    const int t = threadIdx.x;
    int v = (t < NBUK) ? tot[t] : 0;
    tmp[t] = v;
    __syncthreads();
    for (int off = 1; off < 1024; off <<= 1) {
        int a = (t >= off) ? tmp[t - off] : 0;
        __syncthreads();
        tmp[t] += a;
        __syncthreads();
    }
    if (t < NBUK) boff[t] = tmp[t] - v;
    if (t == 0) { boff[NBUK] = N_EDGES; rowptr[N_NODES] = N_EDGES; }
}

// ---------------------------------------------------------------- pass B2: per-bucket run offsets — one WAVE per bucket
__launch_bounds__(256)
__global__ void boffs_kernel(int* __restrict__ h, const int* __restrict__ boff) {
    const int b = (blockIdx.x * blockDim.x + threadIdx.x) >> 6;
    if (b >= NBUK) return;
    const int lane = threadIdx.x & 63;
    int run = boff[b];
    int* row = h + (size_t)b * NCHUNK;
    for (int c0 = 0; c0 < NCHUNK; c0 += 64) {
        int idx = c0 + lane;
        int v = (idx < NCHUNK) ? row[idx] : 0;
        int s = v;
#pragma unroll
        for (int off = 1; off < 64; off <<= 1) {
            int t = __shfl_up(s, off);
            if (lane >= off) s += t;
        }
        if (idx < NCHUNK) row[idx] = run + (s - v);
        run += __shfl(s, 63);
    }
}

// ---------------------------------------------------------------- pass C: scatter to precomputed slots (LDS cursors only)
__launch_bounds__(256)
__global__ void cscatter_kernel(const int* __restrict__ src, const int* __restrict__ dst,
                                const int* __restrict__ h, unsigned* __restrict__ bedges) {
    __shared__ int cur[NBUK];
    const int c = blockIdx.x;
    for (int i = threadIdx.x; i < NBUK; i += 256) cur[i] = h[(size_t)i * NCHUNK + c];
    __syncthreads();
    const int e0 = c * CHUNK;
    const int e1 = min(e0 + CHUNK, N_EDGES);
    const i32x4* pd = (const i32x4*)(dst + e0);
    const i32x4* ps = (const i32x4*)(src + e0);
    const int n4 = (e1 - e0) >> 2;
    for (int i = threadIdx.x; i < n4; i += 256) {
        i32x4 d = __builtin_nontemporal_load(pd + i);
        i32x4 s = __builtin_nontemporal_load(ps + i);
        int slot;
        slot = atomicAdd(&cur[d.x >> 6], 1); bedges[slot] = (unsigned)s.x | ((unsigned)d.x << 16);
        slot = atomicAdd(&cur[d.y >> 6], 1); bedges[slot] = (unsigned)s.y | ((unsigned)d.y << 16);
        slot = atomicAdd(&cur[d.z >> 6], 1); bedges[slot] = (unsigned)s.z | ((unsigned)d.z << 16);
        slot = atomicAdd(&cur[d.w >> 6], 1); bedges[slot] = (unsigned)s.w | ((unsigned)d.w << 16);
    }
}

// ---------------------------------------------------------------- per-bucket CSR build
__launch_bounds__(256)
__global__ void build_kernel(const unsigned* __restrict__ bedges, const int* __restrict__ boff,
                             unsigned short* __restrict__ perm, int* __restrict__ rowptr,
                             float* __restrict__ dinv) {
    __shared__ unsigned e_lds[BCAP];
    __shared__ unsigned short p_lds[BCAP];
    __shared__ int ncnt[64], ncur[64];

    const int b = blockIdx.x;
    const int t = threadIdx.x;
    const int start = boff[b];
    const int end   = boff[b + 1];
    const int cnt   = end - start;
    const bool fits = (cnt <= BCAP);

    if (t < 64) ncnt[t] = 0;
    __syncthreads();

    for (int i = t; i < cnt; i += 256) {
        unsigned e = bedges[start + i];
        if (fits) e_lds[i] = e;
        atomicAdd(&ncnt[(e >> 16) & 63], 1);
    }
    __syncthreads();

    if (t == 0) {
        int a = 0;
        for (int i = 0; i < 64; ++i) { ncur[i] = a; a += ncnt[i]; }
    }
    __syncthreads();

    if (t < 64) {
        int node = b * 64 + t;
        if (node < N_NODES) {
            rowptr[node] = start + ncur[t];
            dinv[node]   = rsqrtf((float)ncnt[t] + 1.0f);   // +1 self loop
        }
    }
    __syncthreads();

    for (int i = t; i < cnt; i += 256) {
        unsigned e = fits ? e_lds[i] : bedges[start + i];
        int slot = atomicAdd(&ncur[(e >> 16) & 63], 1);
        unsigned short s = (unsigned short)(e & 0xFFFFu);
        if (fits) p_lds[slot] = s;
        else      perm[start + slot] = s;
    }
    if (fits) {
        __syncthreads();
        for (int i = t; i < cnt; i += 256) perm[start + i] = p_lds[i];
    }
}

// ---------------------------------------------------------------- fused prep: wt1 | wt2 | BN folds (one launch)
__global__ void prep_kernel(const float* __restrict__ W1, const float* __restrict__ W2,
                            unsigned short* __restrict__ w1t, unsigned short* __restrict__ w2t,
                            const float* __restrict__ g1, const float* __restrict__ be1,
                            const float* __restrict__ m1, const float* __restrict__ v1,
                            const float* __restrict__ b1,
                            const float* __restrict__ g2, const float* __restrict__ be2,
                            const float* __restrict__ m2, const float* __restrict__ v2,
                            const float* __restrict__ b2,
                            float* __restrict__ sc1, float* __restrict__ sh1,
                            float* __restrict__ sc2, float* __restrict__ sh2) {
    const int blk = blockIdx.x;
    const int t = threadIdx.x;
    if (blk < 128) {                       // w1t: 128*256 = 32768 elems
        int i = blk * 256 + t;
        int n = i / IN_F, k = i % IN_F;
        w1t[i] = f2b(W1[(size_t)k * H1_F + n]);
    } else if (blk < 160) {                // w2t: 64*128 = 8192 elems
        int i = (blk - 128) * 256 + t;
        int n = i / H1_F, k = i % H1_F;
        w2t[i] = f2b(W2[(size_t)k * H2_F + n]);
    } else {                               // BN folds: 128 + 64
        if (t < H1_F) {
            float s = g1[t] * rsqrtf(v1[t] + BN_EPS);
            sc1[t] = s;
            sh1[t] = (b1[t] - m1[t]) * s + be1[t];
        } else if (t < H1_F + H2_F) {
            int f = t - H1_F;
            float s = g2[f] * rsqrtf(v2[f] + BN_EPS);
            sc2[f] = s;
            sh2[f] = (b2[f] - m2[f]) * s + be2[f];
        }
    }
}

// ---------------------------------------------------------------- MFMA GEMM, row-major bf16 output
template <int KSTEPS, int NTILES, bool A_BF16>
__launch_bounds__(256)
__global__ void mfma_gemm_kernel(const void* __restrict__ Ap, const unsigned short* __restrict__ BT,
                                 const float* __restrict__ dscale, unsigned short* __restrict__ C,
                                 int M) {
    constexpr int K  = KSTEPS * 32;
    constexpr int NF = NTILES * 16;
    const int wave = threadIdx.x >> 6;
    const int lane = threadIdx.x & 63;
    const int r0   = (blockIdx.x * 4 + wave) * 16;
    const int m    = lane & 15;
    const int kb   = lane >> 4;

    int arow = r0 + m;
    if (arow >= M) arow = M - 1;

    f32x4 acc[NTILES];
#pragma unroll
    for (int nt = 0; nt < NTILES; ++nt) acc[nt] = (f32x4)(0.f);

#pragma unroll
    for (int ks = 0; ks < KSTEPS; ++ks) {
        const int k0 = ks * 32 + kb * 8;
        bf16x8 a;
        if constexpr (A_BF16) {
            a = *(const bf16x8*)((const unsigned short*)Ap + (size_t)arow * K + k0);
        } else {
            const float* af = (const float*)Ap + (size_t)arow * K + k0;
            f32x4 lo = __builtin_nontemporal_load((const f32x4*)af);
            f32x4 hi = __builtin_nontemporal_load((const f32x4*)(af + 4));
            union { bf16x8 v; unsigned short u[8]; } pk;
            pk.u[0] = f2b(lo.x); pk.u[1] = f2b(lo.y); pk.u[2] = f2b(lo.z); pk.u[3] = f2b(lo.w);
            pk.u[4] = f2b(hi.x); pk.u[5] = f2b(hi.y); pk.u[6] = f2b(hi.z); pk.u[7] = f2b(hi.w);
            a = pk.v;
        }
#pragma unroll
        for (int nt = 0; nt < NTILES; ++nt) {
            bf16x8 b = *(const bf16x8*)(BT + (size_t)(nt * 16 + m) * K + k0);
            acc[nt] = __builtin_amdgcn_mfma_f32_16x16x32_bf16(a, b, acc[nt], 0, 0, 0);
        }
    }

#pragma unroll
    for (int reg = 0; reg < 4; ++reg) {
        const int r = r0 + kb * 4 + reg;
        if (r < M) {
            const float ds = dscale[r];
#pragma unroll
            for (int nt = 0; nt < NTILES; ++nt)
                C[(size_t)r * NF + nt * 16 + m] = f2b(acc[nt][reg] * ds);
        }
    }
}

// ---------------------------------------------------------------- fused aggregation, NPW nodes per wave
//   LPE=HF/8 lanes per edge (16B bf16x8); G=64/LPE edge groups; prologue batched, BN hoisted
template <int HF, bool FINAL>
__launch_bounds__(256)
__global__ void agg_kernel(const int* __restrict__ rowptr, const unsigned short* __restrict__ perm,
                           const unsigned short* __restrict__ xw, const float* __restrict__ dinv,
                           const float* __restrict__ sc, const float* __restrict__ sh,
                           const float* __restrict__ Wl, const float* __restrict__ bl,
                           void* __restrict__ outp) {
    constexpr int LPE = HF / 8;
    constexpr int G   = 64 / LPE;
    const int wid  = (blockIdx.x * blockDim.x + threadIdx.x) >> 6;
    const int n0   = wid * NPW;
    if (n0 >= N_NODES) return;
    const int lane = threadIdx.x & 63;
    const int grp  = lane / LPE;
    const int fl   = (lane % LPE) * 8;

    // hoisted per-feature constants (identical across the node loop)
    f32x4 scl = *(const f32x4*)(sc + fl);
    f32x4 sch = *(const f32x4*)(sc + fl + 4);
    f32x4 shl = *(const f32x4*)(sh + fl);
    f32x4 shh = *(const f32x4*)(sh + fl + 4);
    float wl0[8], wl1[8];
    if constexpr (FINAL) {
#pragma unroll
        for (int i = 0; i < 8; ++i) {
            wl0[i] = Wl[(fl + i) * 2 + 0];
            wl1[i] = Wl[(fl + i) * 2 + 1];
        }
    }

    // batched prologue: lanes 0..NPW hold rowptr, lanes 0..NPW-1 hold dinv
    int rp = 0;
    if (lane <= NPW) rp = rowptr[n0 + lane];          // n0+NPW <= N_NODES (50000 % NPW == 0)
    float dvl = (lane < NPW) ? dinv[n0 + lane] : 0.f;

    for (int k = 0; k < NPW; ++k) {
        const int node  = n0 + k;
        const int start = __shfl(rp, k);
        const int end   = __shfl(rp, k + 1);

        float aA[8];
#pragma unroll
        for (int i = 0; i < 8; ++i) aA[i] = 0.f;

        if (grp == 0) {   // self term
            u32x4 u = *(const u32x4*)(xw + (size_t)node * HF + fl);
#pragma unroll
            for (int i = 0; i < 4; ++i) add2(aA[2 * i], aA[2 * i + 1], u[i]);
        }

        for (int base = start; base < end; base += 64) {
            int pidx = base + lane;
            int pv = (int)__builtin_nontemporal_load(perm + (pidx < end ? pidx : end - 1));
            int ne = end - base;
            if (ne > 64) ne = 64;
            if (ne == 64) {
#pragma unroll
                for (int j = 0; j < 64; j += G) {
                    int s = __shfl(pv, j + grp);
                    u32x4 u = *(const u32x4*)(xw + (size_t)s * HF + fl);
#pragma unroll
                    for (int i = 0; i < 4; ++i) add2(aA[2 * i], aA[2 * i + 1], u[i]);
                }
            } else {
                for (int j = 0; j < ne; j += G) {
                    int s = __shfl(pv, j + grp);
                    if (j + grp < ne) {
                        u32x4 u = *(const u32x4*)(xw + (size_t)s * HF + fl);
#pragma unroll
                        for (int i = 0; i < 4; ++i) add2(aA[2 * i], aA[2 * i + 1], u[i]);
                    }
                }
            }
        }

        // reduce across edge groups
#pragma unroll
        for (int off = LPE; off < 64; off <<= 1)
#pragma unroll
            for (int i = 0; i < 8; ++i) aA[i] += __shfl_xor(aA[i], off);

        const float dv = __shfl(dvl, k);
        float y[8];
#pragma unroll
        for (int i = 0; i < 4; ++i) {
            y[i]     = fmaxf(aA[i] * (dv * scl[i]) + shl[i], 0.f);
            y[i + 4] = fmaxf(aA[i + 4] * (dv * sch[i]) + shh[i], 0.f);
        }

        if constexpr (!FINAL) {
            if (lane < LPE) {
                u32x4 o;
#pragma unroll
                for (int i = 0; i < 4; ++i)
                    o[i] = (unsigned)f2b(y[2 * i]) | ((unsigned)f2b(y[2 * i + 1]) << 16);
                __builtin_nontemporal_store(o, (u32x4*)((unsigned short*)outp + (size_t)node * HF + fl));
            }
        } else {
            float p0 = 0.f, p1 = 0.f;
#pragma unroll
            for (int i = 0; i < 8; ++i) {
                p0 += y[i] * wl0[i];
                p1 += y[i] * wl1[i];
            }
#pragma unroll
            for (int off = 1; off < LPE; off <<= 1) {
                p0 += __shfl_xor(p0, off);
                p1 += __shfl_xor(p1, off);
            }
            if (lane == 0) {
                float* o = (float*)outp;
                o[(size_t)node * 2 + 0] = p0 + bl[0];
                o[(size_t)node * 2 + 1] = p1 + bl[1];
            }
        }
    }
}

// ---------------------------------------------------------------- launcher
extern "C" void kernel_launch(void* const* d_in, const int* in_sizes, int n_in,
                              void* d_out, int out_size, void* d_ws, size_t ws_size,
                              hipStream_t stream) {
    const float* x   = (const float*)d_in[0];
    const int*   ei  = (const int*)d_in[1];
    const float* W1  = (const float*)d_in[2];
    const float* b1  = (const float*)d_in[3];
    const float* g1  = (const float*)d_in[4];
    const float* be1 = (const float*)d_in[5];
    const float* m1  = (const float*)d_in[6];
    const float* v1  = (const float*)d_in[7];
    const float* W2  = (const float*)d_in[8];
    const float* b2  = (const float*)d_in[9];
    const float* g2  = (const float*)d_in[10];
    const float* be2 = (const float*)d_in[11];
    const float* m2  = (const float*)d_in[12];
    const float* v2  = (const float*)d_in[13];
    const float* Wl  = (const float*)d_in[14];
    const float* bl  = (const float*)d_in[15];

    const int* src = ei;            // edge_index[0]
    const int* dst = ei + N_EDGES;  // edge_index[1]

    // workspace layout (4B units)
    int*            h      = (int*)d_ws;                          // NBUK*NCHUNK (bucket-major)
    int*            tot    = h + (size_t)NBUK * NCHUNK;           // 1024
    int*            boff   = tot + 1024;                          // 1024
    int*            rowptr = boff + 1024;                         // 50016
    float*          dinv   = (float*)(rowptr + 50016);            // 50016
    float*          sc1    = dinv + 50016;                        // 128
    float*          sh1    = sc1 + 128;                           // 128
    float*          sc2    = sh1 + 128;                           // 64
    float*          sh2    = sc2 + 64;                            // 64
    unsigned*       bedges = (unsigned*)(sh2 + 64);               // E
    unsigned short* perm   = (unsigned short*)(bedges + N_EDGES); // E ushorts
    unsigned short* xwb    = perm + N_EDGES;                      // N*128 bf16 (row-major)
    unsigned short* h1b    = xwb + (size_t)N_NODES * H1_F;        // N*128 bf16 (row-major)
    unsigned short* w1t    = h1b + (size_t)N_NODES * H1_F;        // 128*256 bf16
    unsigned short* w2t    = w1t + H1_F * IN_F;                   // 64*128 bf16

    hipMemsetAsync(tot, 0, 1024 * sizeof(int), stream);

    // ---- CSR build ----
    chist_kernel<<<NCHUNK, 256, 0, stream>>>(dst, h, tot);
    bscan_kernel<<<1, 1024, 0, stream>>>(tot, boff, rowptr);
    boffs_kernel<<<(NBUK * 64 + 255) / 256, 256, 0, stream>>>(h, boff);
    cscatter_kernel<<<NCHUNK, 256, 0, stream>>>(src, dst, h, bedges);
    build_kernel<<<NBUK, 256, 0, stream>>>(bedges, boff, perm, rowptr, dinv);

    // ---- fused weight/BN prep (one launch) ----
    prep_kernel<<<161, 256, 0, stream>>>(W1, W2, w1t, w2t,
                                         g1, be1, m1, v1, b1,
                                         g2, be2, m2, v2, b2,
                                         sc1, sh1, sc2, sh2);

    // ---- layer 1 ----
    mfma_gemm_kernel<IN_F / 32, H1_F / 16, false><<<(N_NODES + 63) / 64, 256, 0, stream>>>(
        x, w1t, dinv, xwb, N_NODES);
    agg_kernel<H1_F, false><<<(N_NODES / NPW + 3) / 4, 256, 0, stream>>>(
        rowptr, perm, xwb, dinv, sc1, sh1, nullptr, nullptr, h1b);

    // ---- layer 2 + fused final linear ----
    mfma_gemm_kernel<H1_F / 32, H2_F / 16, true><<<(N_NODES + 63) / 64, 256, 0, stream>>>(
        h1b, w2t, dinv, xwb, N_NODES);
    agg_kernel<H2_F, true><<<(N_NODES / NPW + 3) / 4, 256, 0, stream>>>(
        rowptr, perm, xwb, dinv, sc2, sh2, Wl, bl, (float*)d_out);
}

// Round 13
// 287.169 us; speedup vs baseline: 1.0436x; 1.0436x over previous
//
#include <hip/hip_runtime.h>

#define N_NODES 50000
#define N_EDGES 1600000
#define IN_F 256
#define H1_F 128
#define H2_F 64
#define OUT_F 2
#define BN_EPS 1e-5f

#define NBUK 782          // ceil(50000/64) buckets of 64 nodes
#define BCAP 3584         // LDS edge capacity per bucket in build (avg 2048)
#define CHUNK 4096        // edges per chunk
#define NCHUNK 391        // ceil(1600000/4096)
#define FC 32             // features per agg1 chunk (slice = N*32*2B = 3.2MB < 4MiB L2/XCD)

typedef __attribute__((ext_vector_type(8))) short bf16x8;   // 8 bf16 in 4 VGPRs
typedef __attribute__((ext_vector_type(4))) float f32x4;
typedef __attribute__((ext_vector_type(4))) int   i32x4;
typedef __attribute__((ext_vector_type(4))) unsigned u32x4;

// ---------------------------------------------------------------- bf16 helpers
__device__ __forceinline__ unsigned short f2b(float f) {
    union { float f; unsigned u; } v; v.f = f;
    unsigned r = (v.u + 0x7FFFu + ((v.u >> 16) & 1u)) >> 16;
    return (unsigned short)r;
}
__device__ __forceinline__ float b2f(unsigned short b) {
    union { unsigned u; float f; } v; v.u = ((unsigned)b) << 16;
    return v.f;
}
__device__ __forceinline__ void add2(float& a0, float& a1, unsigned u) {
    union { unsigned u; float f; } lo, hi;
    lo.u = u << 16;
    hi.u = u & 0xFFFF0000u;
    a0 += lo.f; a1 += hi.f;
}

// ---------------------------------------------------------------- pass A: per-chunk bucket histogram (bucket-major h)
__launch_bounds__(256)
__global__ void chist_kernel(const int* __restrict__ dst, int* __restrict__ h,
                             int* __restrict__ tot) {
    __shared__ int lh[NBUK];
    const int c = blockIdx.x;
    for (int i = threadIdx.x; i < NBUK; i += 256) lh[i] = 0;
    __syncthreads();
    const int e0 = c * CHUNK;
    const int e1 = min(e0 + CHUNK, N_EDGES);
    const i32x4* p = (const i32x4*)(dst + e0);
    const int n4 = (e1 - e0) >> 2;
    for (int i = threadIdx.x; i < n4; i += 256) {
        i32x4 d = __builtin_nontemporal_load(p + i);
        atomicAdd(&lh[d.x >> 6], 1);
        atomicAdd(&lh[d.y >> 6], 1);
        atomicAdd(&lh[d.z >> 6], 1);
        atomicAdd(&lh[d.w >> 6], 1);
    }
    __syncthreads();
    for (int i = threadIdx.x; i < NBUK; i += 256) {
        int v = lh[i];
        h[(size_t)i * NCHUNK + c] = v;
        if (v) atomicAdd(&tot[i], v);      // fire-and-forget
    }
}

// ---------------------------------------------------------------- pass B1: scan 782 bucket totals (1 block)
__global__ void bscan_kernel(const int* __restrict__ tot, int* __restrict__ boff,
                             int* __restrict__ rowptr) {
    __shared__ int tmp[1024];
    const int t = threadIdx.x;
    int v = (t < NBUK) ? tot[t] : 0;
    tmp[t] = v;
    __syncthreads();
    for (int off = 1; off < 1024; off <<= 1) {
        int a = (t >= off) ? tmp[t - off] : 0;
        __syncthreads();
        tmp[t] += a;
        __syncthreads();
    }
    if (t < NBUK) boff[t] = tmp[t] - v;
    if (t == 0) { boff[NBUK] = N_EDGES; rowptr[N_NODES] = N_EDGES; }
}

// ---------------------------------------------------------------- pass B2: per-bucket run offsets — one WAVE per bucket
__launch_bounds__(256)
__global__ void boffs_kernel(int* __restrict__ h, const int* __restrict__ boff) {
    const int b = (blockIdx.x * blockDim.x + threadIdx.x) >> 6;
    if (b >= NBUK) return;
    const int lane = threadIdx.x & 63;
    int run = boff[b];
    int* row = h + (size_t)b * NCHUNK;
    for (int c0 = 0; c0 < NCHUNK; c0 += 64) {
        int idx = c0 + lane;
        int v = (idx < NCHUNK) ? row[idx] : 0;
        int s = v;
#pragma unroll
        for (int off = 1; off < 64; off <<= 1) {
            int t = __shfl_up(s, off);
            if (lane >= off) s += t;
        }
        if (idx < NCHUNK) row[idx] = run + (s - v);
        run += __shfl(s, 63);
    }
}

// ---------------------------------------------------------------- pass C: scatter to precomputed slots (LDS cursors only)
__launch_bounds__(256)
__global__ void cscatter_kernel(const int* __restrict__ src, const int* __restrict__ dst,
                                const int* __restrict__ h, unsigned* __restrict__ bedges) {
    __shared__ int cur[NBUK];
    const int c = blockIdx.x;
    for (int i = threadIdx.x; i < NBUK; i += 256) cur[i] = h[(size_t)i * NCHUNK + c];
    __syncthreads();
    const int e0 = c * CHUNK;
    const int e1 = min(e0 + CHUNK, N_EDGES);
    const i32x4* pd = (const i32x4*)(dst + e0);
    const i32x4* ps = (const i32x4*)(src + e0);
    const int n4 = (e1 - e0) >> 2;
    for (int i = threadIdx.x; i < n4; i += 256) {
        i32x4 d = __builtin_nontemporal_load(pd + i);
        i32x4 s = __builtin_nontemporal_load(ps + i);
        int slot;
        slot = atomicAdd(&cur[d.x >> 6], 1); bedges[slot] = (unsigned)s.x | ((unsigned)d.x << 16);
        slot = atomicAdd(&cur[d.y >> 6], 1); bedges[slot] = (unsigned)s.y | ((unsigned)d.y << 16);
        slot = atomicAdd(&cur[d.z >> 6], 1); bedges[slot] = (unsigned)s.z | ((unsigned)d.z << 16);
        slot = atomicAdd(&cur[d.w >> 6], 1); bedges[slot] = (unsigned)s.w | ((unsigned)d.w << 16);
    }
}

// ---------------------------------------------------------------- per-bucket CSR build
__launch_bounds__(256)
__global__ void build_kernel(const unsigned* __restrict__ bedges, const int* __restrict__ boff,
                             unsigned short* __restrict__ perm, int* __restrict__ rowptr,
                             float* __restrict__ dinv) {
    __shared__ unsigned e_lds[BCAP];
    __shared__ unsigned short p_lds[BCAP];
    __shared__ int ncnt[64], ncur[64];

    const int b = blockIdx.x;
    const int t = threadIdx.x;
    const int start = boff[b];
    const int end   = boff[b + 1];
    const int cnt   = end - start;
    const bool fits = (cnt <= BCAP);

    if (t < 64) ncnt[t] = 0;
    __syncthreads();

    for (int i = t; i < cnt; i += 256) {
        unsigned e = bedges[start + i];
        if (fits) e_lds[i] = e;
        atomicAdd(&ncnt[(e >> 16) & 63], 1);
    }
    __syncthreads();

    if (t == 0) {
        int a = 0;
        for (int i = 0; i < 64; ++i) { ncur[i] = a; a += ncnt[i]; }
    }
    __syncthreads();

    if (t < 64) {
        int node = b * 64 + t;
        if (node < N_NODES) {
            rowptr[node] = start + ncur[t];
            dinv[node]   = rsqrtf((float)ncnt[t] + 1.0f);   // +1 self loop
        }
    }
    __syncthreads();

    for (int i = t; i < cnt; i += 256) {
        unsigned e = fits ? e_lds[i] : bedges[start + i];
        int slot = atomicAdd(&ncur[(e >> 16) & 63], 1);
        unsigned short s = (unsigned short)(e & 0xFFFFu);
        if (fits) p_lds[slot] = s;
        else      perm[start + slot] = s;
    }
    if (fits) {
        __syncthreads();
        for (int i = t; i < cnt; i += 256) perm[start + i] = p_lds[i];
    }
}

// ---------------------------------------------------------------- fused prep: wt1 | wt2 | BN folds (one launch)
__global__ void prep_kernel(const float* __restrict__ W1, const float* __restrict__ W2,
                            unsigned short* __restrict__ w1t, unsigned short* __restrict__ w2t,
                            const float* __restrict__ g1, const float* __restrict__ be1,
                            const float* __restrict__ m1, const float* __restrict__ v1,
                            const float* __restrict__ b1,
                            const float* __restrict__ g2, const float* __restrict__ be2,
                            const float* __restrict__ m2, const float* __restrict__ v2,
                            const float* __restrict__ b2,
                            float* __restrict__ sc1, float* __restrict__ sh1,
                            float* __restrict__ sc2, float* __restrict__ sh2) {
    const int blk = blockIdx.x;
    const int t = threadIdx.x;
    if (blk < 128) {                       // w1t: 128*256
        int i = blk * 256 + t;
        int n = i / IN_F, k = i % IN_F;
        w1t[i] = f2b(W1[(size_t)k * H1_F + n]);
    } else if (blk < 160) {                // w2t: 64*128
        int i = (blk - 128) * 256 + t;
        int n = i / H1_F, k = i % H1_F;
        w2t[i] = f2b(W2[(size_t)k * H2_F + n]);
    } else {
        if (t < H1_F) {
            float s = g1[t] * rsqrtf(v1[t] + BN_EPS);
            sc1[t] = s;
            sh1[t] = (b1[t] - m1[t]) * s + be1[t];
        } else if (t < H1_F + H2_F) {
            int f = t - H1_F;
            float s = g2[f] * rsqrtf(v2[f] + BN_EPS);
            sc2[f] = s;
            sh2[f] = (b2[f] - m2[f]) * s + be2[f];
        }
    }
}

// ---------------------------------------------------------------- MFMA GEMM
// CHUNK_OUT: C layout [f>>5][r][f&31]; else row-major [r][NF].
// A_CHUNKED: A is chunk-major bf16 [ks][r][32]; else row-major fp32.
template <int KSTEPS, int NTILES, bool A_CHUNKED, bool CHUNK_OUT>
__launch_bounds__(256)
__global__ void mfma_gemm_kernel(const void* __restrict__ Ap, const unsigned short* __restrict__ BT,
                                 const float* __restrict__ dscale, unsigned short* __restrict__ C,
                                 int M) {
    constexpr int K  = KSTEPS * 32;
    constexpr int NF = NTILES * 16;
    const int wave = threadIdx.x >> 6;
    const int lane = threadIdx.x & 63;
    const int r0   = (blockIdx.x * 4 + wave) * 16;
    const int m    = lane & 15;
    const int kb   = lane >> 4;

    int arow = r0 + m;
    if (arow >= M) arow = M - 1;

    f32x4 acc[NTILES];
#pragma unroll
    for (int nt = 0; nt < NTILES; ++nt) acc[nt] = (f32x4)(0.f);

#pragma unroll
    for (int ks = 0; ks < KSTEPS; ++ks) {
        const int k0 = ks * 32 + kb * 8;
        bf16x8 a;
        if constexpr (A_CHUNKED) {
            a = *(const bf16x8*)((const unsigned short*)Ap +
                                 (size_t)ks * N_NODES * FC + (size_t)arow * FC + kb * 8);
        } else {
            const float* af = (const float*)Ap + (size_t)arow * K + k0;
            f32x4 lo = __builtin_nontemporal_load((const f32x4*)af);
            f32x4 hi = __builtin_nontemporal_load((const f32x4*)(af + 4));
            union { bf16x8 v; unsigned short u[8]; } pk;
            pk.u[0] = f2b(lo.x); pk.u[1] = f2b(lo.y); pk.u[2] = f2b(lo.z); pk.u[3] = f2b(lo.w);
            pk.u[4] = f2b(hi.x); pk.u[5] = f2b(hi.y); pk.u[6] = f2b(hi.z); pk.u[7] = f2b(hi.w);
            a = pk.v;
        }
#pragma unroll
        for (int nt = 0; nt < NTILES; ++nt) {
            bf16x8 b = *(const bf16x8*)(BT + (size_t)(nt * 16 + m) * K + k0);
            acc[nt] = __builtin_amdgcn_mfma_f32_16x16x32_bf16(a, b, acc[nt], 0, 0, 0);
        }
    }

#pragma unroll
    for (int reg = 0; reg < 4; ++reg) {
        const int r = r0 + kb * 4 + reg;
        if (r < M) {
            const float ds = dscale[r];
#pragma unroll
            for (int nt = 0; nt < NTILES; ++nt) {
                if constexpr (CHUNK_OUT) {
                    C[(size_t)(nt >> 1) * N_NODES * FC + (size_t)r * FC + ((nt & 1) << 4) + m] =
                        f2b(acc[nt][reg] * ds);
                } else {
                    C[(size_t)r * NF + nt * 16 + m] = f2b(acc[nt][reg] * ds);
                }
            }
        }
    }
}

// ---------------------------------------------------------------- agg1: chunked FC=32, wide 16B loads
//   blockIdx.y = chunk c (slice 3.2MB, L2-resident); wave/node; LPE=4 lanes/edge; G=16 edges in flight
__launch_bounds__(256)
__global__ void agg_chunk_kernel(const int* __restrict__ rowptr, const unsigned short* __restrict__ perm,
                                 const unsigned short* __restrict__ xw,   // [c][node][FC]
                                 const float* __restrict__ dinv,
                                 const float* __restrict__ sc, const float* __restrict__ sh,
                                 unsigned short* __restrict__ out) {      // [c][node][FC]
    const int c = blockIdx.y;
    const unsigned short* xc = xw + (size_t)c * N_NODES * FC;
    const int wave = threadIdx.x >> 6;
    const int node = blockIdx.x * 4 + wave;
    if (node >= N_NODES) return;
    const int lane = threadIdx.x & 63;
    const int grp  = lane >> 2;          // 16 edge groups
    const int fl   = (lane & 3) << 3;    // 8 feats per lane within chunk

    float aA[8];
#pragma unroll
    for (int i = 0; i < 8; ++i) aA[i] = 0.f;

    if (grp == 0) {   // self term
        u32x4 u = *(const u32x4*)(xc + (size_t)node * FC + fl);
#pragma unroll
        for (int i = 0; i < 4; ++i) add2(aA[2 * i], aA[2 * i + 1], u[i]);
    }

    const int start = rowptr[node];
    const int end   = rowptr[node + 1];
    for (int base = start; base < end; base += 64) {
        int pidx = base + lane;
        int pv = (int)__builtin_nontemporal_load(perm + (pidx < end ? pidx : end - 1));
        int ne = end - base;
        if (ne > 64) ne = 64;
        if (ne == 64) {
#pragma unroll
            for (int j = 0; j < 64; j += 16) {
                int s = __shfl(pv, j + grp);
                u32x4 u = *(const u32x4*)(xc + (size_t)s * FC + fl);
#pragma unroll
                for (int i = 0; i < 4; ++i) add2(aA[2 * i], aA[2 * i + 1], u[i]);
            }
        } else {
            for (int j = 0; j < ne; j += 16) {
                int s = __shfl(pv, j + grp);
                if (j + grp < ne) {
                    u32x4 u = *(const u32x4*)(xc + (size_t)s * FC + fl);
#pragma unroll
                    for (int i = 0; i < 4; ++i) add2(aA[2 * i], aA[2 * i + 1], u[i]);
                }
            }
        }
    }

    // reduce across 16 edge groups (lanes 4 apart share a feature slice)
#pragma unroll
    for (int off = 4; off < 64; off <<= 1)
#pragma unroll
        for (int i = 0; i < 8; ++i) aA[i] += __shfl_xor(aA[i], off);

    if (lane < 4) {
        const float dv = dinv[node];
        const int f = c * FC + fl;
        f32x4 scl = *(const f32x4*)(sc + f);
        f32x4 sch = *(const f32x4*)(sc + f + 4);
        f32x4 shl = *(const f32x4*)(sh + f);
        f32x4 shh = *(const f32x4*)(sh + f + 4);
        float y[8];
#pragma unroll
        for (int i = 0; i < 4; ++i) {
            y[i]     = fmaxf(aA[i] * (dv * scl[i]) + shl[i], 0.f);
            y[i + 4] = fmaxf(aA[i + 4] * (dv * sch[i]) + shh[i], 0.f);
        }
        u32x4 o;
#pragma unroll
        for (int i = 0; i < 4; ++i)
            o[i] = (unsigned)f2b(y[2 * i]) | ((unsigned)f2b(y[2 * i + 1]) << 16);
        __builtin_nontemporal_store(o, (u32x4*)(out + (size_t)c * N_NODES * FC + (size_t)node * FC + fl));
    }
}

// ---------------------------------------------------------------- agg2: row-major HF=64, fused 64->2 final (round-11 proven)
__launch_bounds__(256)
__global__ void agg_final_kernel(const int* __restrict__ rowptr, const unsigned short* __restrict__ perm,
                                 const unsigned short* __restrict__ xw, const float* __restrict__ dinv,
                                 const float* __restrict__ sc, const float* __restrict__ sh,
                                 const float* __restrict__ Wl, const float* __restrict__ bl,
                                 float* __restrict__ outp) {
    constexpr int HF  = 64;
    constexpr int LPE = 8;
    constexpr int G   = 8;
    const int wave = threadIdx.x >> 6;
    const int node = blockIdx.x * 4 + wave;
    if (node >= N_NODES) return;
    const int lane = threadIdx.x & 63;
    const int grp  = lane / LPE;
    const int fl   = (lane % LPE) * 8;

    float aA[8];
#pragma unroll
    for (int i = 0; i < 8; ++i) aA[i] = 0.f;

    if (grp == 0) {
        u32x4 u = *(const u32x4*)(xw + (size_t)node * HF + fl);
#pragma unroll
        for (int i = 0; i < 4; ++i) add2(aA[2 * i], aA[2 * i + 1], u[i]);
    }

    const int start = rowptr[node];
    const int end   = rowptr[node + 1];
    for (int base = start; base < end; base += 64) {
        int pidx = base + lane;
        int pv = (int)__builtin_nontemporal_load(perm + (pidx < end ? pidx : end - 1));
        int ne = end - base;
        if (ne > 64) ne = 64;
        if (ne == 64) {
#pragma unroll
            for (int j = 0; j < 64; j += G) {
                int s = __shfl(pv, j + grp);
                u32x4 u = *(const u32x4*)(xw + (size_t)s * HF + fl);
#pragma unroll
                for (int i = 0; i < 4; ++i) add2(aA[2 * i], aA[2 * i + 1], u[i]);
            }
        } else {
            for (int j = 0; j < ne; j += G) {
                int s = __shfl(pv, j + grp);
                if (j + grp < ne) {
                    u32x4 u = *(const u32x4*)(xw + (size_t)s * HF + fl);
#pragma unroll
                    for (int i = 0; i < 4; ++i) add2(aA[2 * i], aA[2 * i + 1], u[i]);
                }
            }
        }
    }

#pragma unroll
    for (int off = LPE; off < 64; off <<= 1)
#pragma unroll
        for (int i = 0; i < 8; ++i) aA[i] += __shfl_xor(aA[i], off);

    const float dv = dinv[node];
    f32x4 scl = *(const f32x4*)(sc + fl);
    f32x4 sch = *(const f32x4*)(sc + fl + 4);
    f32x4 shl = *(const f32x4*)(sh + fl);
    f32x4 shh = *(const f32x4*)(sh + fl + 4);
    float y[8];
#pragma unroll
    for (int i = 0; i < 4; ++i) {
        y[i]     = fmaxf(aA[i] * (dv * scl[i]) + shl[i], 0.f);
        y[i + 4] = fmaxf(aA[i + 4] * (dv * sch[i]) + shh[i], 0.f);
    }

    float p0 = 0.f, p1 = 0.f;
#pragma unroll
    for (int i = 0; i < 8; ++i) {
        p0 += y[i] * Wl[(fl + i) * 2 + 0];
        p1 += y[i] * Wl[(fl + i) * 2 + 1];
    }
#pragma unroll
    for (int off = 1; off < LPE; off <<= 1) {
        p0 += __shfl_xor(p0, off);
        p1 += __shfl_xor(p1, off);
    }
    if (lane == 0) {
        outp[(size_t)node * 2 + 0] = p0 + bl[0];
        outp[(size_t)node * 2 + 1] = p1 + bl[1];
    }
}

// ---------------------------------------------------------------- launcher
extern "C" void kernel_launch(void* const* d_in, const int* in_sizes, int n_in,
                              void* d_out, int out_size, void* d_ws, size_t ws_size,
                              hipStream_t stream) {
    const float* x   = (const float*)d_in[0];
    const int*   ei  = (const int*)d_in[1];
    const float* W1  = (const float*)d_in[2];
    const float* b1  = (const float*)d_in[3];
    const float* g1  = (const float*)d_in[4];
    const float* be1 = (const float*)d_in[5];
    const float* m1  = (const float*)d_in[6];
    const float* v1  = (const float*)d_in[7];
    const float* W2  = (const float*)d_in[8];
    const float* b2  = (const float*)d_in[9];
    const float* g2  = (const float*)d_in[10];
    const float* be2 = (const float*)d_in[11];
    const float* m2  = (const float*)d_in[12];
    const float* v2  = (const float*)d_in[13];
    const float* Wl  = (const float*)d_in[14];
    const float* bl  = (const float*)d_in[15];

    const int* src = ei;            // edge_index[0]
    const int* dst = ei + N_EDGES;  // edge_index[1]

    // workspace layout (4B units)
    int*            h      = (int*)d_ws;                          // NBUK*NCHUNK (bucket-major)
    int*            tot    = h + (size_t)NBUK * NCHUNK;           // 1024
    int*            boff   = tot + 1024;                          // 1024
    int*            rowptr = boff + 1024;                         // 50016
    float*          dinv   = (float*)(rowptr + 50016);            // 50016
    float*          sc1    = dinv + 50016;                        // 128
    float*          sh1    = sc1 + 128;                           // 128
    float*          sc2    = sh1 + 128;                           // 64
    float*          sh2    = sc2 + 64;                            // 64
    unsigned*       bedges = (unsigned*)(sh2 + 64);               // E
    unsigned short* perm   = (unsigned short*)(bedges + N_EDGES); // E ushorts
    unsigned short* xwb    = perm + N_EDGES;                      // N*128 bf16
    unsigned short* h1b    = xwb + (size_t)N_NODES * H1_F;        // N*128 bf16
    unsigned short* w1t    = h1b + (size_t)N_NODES * H1_F;        // 128*256 bf16
    unsigned short* w2t    = w1t + H1_F * IN_F;                   // 64*128 bf16

    hipMemsetAsync(tot, 0, 1024 * sizeof(int), stream);

    // ---- CSR build ----
    chist_kernel<<<NCHUNK, 256, 0, stream>>>(dst, h, tot);
    bscan_kernel<<<1, 1024, 0, stream>>>(tot, boff, rowptr);
    boffs_kernel<<<(NBUK * 64 + 255) / 256, 256, 0, stream>>>(h, boff);
    cscatter_kernel<<<NCHUNK, 256, 0, stream>>>(src, dst, h, bedges);
    build_kernel<<<NBUK, 256, 0, stream>>>(bedges, boff, perm, rowptr, dinv);

    // ---- fused weight/BN prep ----
    prep_kernel<<<161, 256, 0, stream>>>(W1, W2, w1t, w2t,
                                         g1, be1, m1, v1, b1,
                                         g2, be2, m2, v2, b2,
                                         sc1, sh1, sc2, sh2);

    // ---- layer 1: gemm -> chunk-major; chunked agg (4 L2-resident passes) ----
    mfma_gemm_kernel<IN_F / 32, H1_F / 16, false, true><<<(N_NODES + 63) / 64, 256, 0, stream>>>(
        x, w1t, dinv, xwb, N_NODES);
    agg_chunk_kernel<<<dim3((N_NODES + 3) / 4, H1_F / FC), 256, 0, stream>>>(
        rowptr, perm, xwb, dinv, sc1, sh1, h1b);

    // ---- layer 2: gemm reads chunk-major A, writes row-major; fused final agg ----
    mfma_gemm_kernel<H1_F / 32, H2_F / 16, true, false><<<(N_NODES + 63) / 64, 256, 0, stream>>>(
        h1b, w2t, dinv, xwb, N_NODES);
    agg_final_kernel<<<(N_NODES + 3) / 4, 256, 0, stream>>>(
        rowptr, perm, xwb, dinv, sc2, sh2, Wl, bl, (float*)d_out);
}

// Round 15
// 253.693 us; speedup vs baseline: 1.1813x; 1.1320x over previous
//
#include <hip/hip_runtime.h>

#define N_NODES 50000
#define N_EDGES 1600000
#define IN_F 256
#define H1_F 128
#define H2_F 64
#define OUT_F 2
#define BN_EPS 1e-5f

#define NBUK 782          // ceil(50000/64) buckets of 64 nodes
#define BCAP 3584         // LDS edge capacity per bucket in build (avg 2048)
#define CHUNK 4096        // edges per chunk
#define NCHUNK 391        // ceil(1600000/4096)

typedef __attribute__((ext_vector_type(8))) short bf16x8;
typedef __attribute__((ext_vector_type(4))) float f32x4;
typedef __attribute__((ext_vector_type(4))) int   i32x4;
typedef __attribute__((ext_vector_type(4))) unsigned u32x4;

// ---------------------------------------------------------------- bf16 helpers
__device__ __forceinline__ unsigned short f2b(float f) {
    union { float f; unsigned u; } v; v.f = f;
    unsigned r = (v.u + 0x7FFFu + ((v.u >> 16) & 1u)) >> 16;
    return (unsigned short)r;
}
__device__ __forceinline__ float b2f(unsigned short b) {
    union { unsigned u; float f; } v; v.u = ((unsigned)b) << 16;
    return v.f;
}
__device__ __forceinline__ void add2(float& a0, float& a1, unsigned u) {
    union { unsigned u; float f; } lo, hi;
    lo.u = u << 16;
    hi.u = u & 0xFFFF0000u;
    a0 += lo.f; a1 += hi.f;
}

// ---------------------------------------------------------------- chist + prep fused
//   blocks [0,NCHUNK): per-chunk bucket histogram (bucket-major h) + tot atomics
//   blocks [NCHUNK, NCHUNK+161): weight transpose/convert + BN folds
__launch_bounds__(256)
__global__ void chist_prep_kernel(const int* __restrict__ dst, int* __restrict__ h,
                                  int* __restrict__ tot,
                                  const float* __restrict__ W1, const float* __restrict__ W2,
                                  unsigned short* __restrict__ w1t, unsigned short* __restrict__ w2t,
                                  const float* __restrict__ g1, const float* __restrict__ be1,
                                  const float* __restrict__ m1, const float* __restrict__ v1,
                                  const float* __restrict__ b1,
                                  const float* __restrict__ g2, const float* __restrict__ be2,
                                  const float* __restrict__ m2, const float* __restrict__ v2,
                                  const float* __restrict__ b2,
                                  float* __restrict__ sc1, float* __restrict__ sh1,
                                  float* __restrict__ sc2, float* __restrict__ sh2) {
    const int blk = blockIdx.x;
    const int t   = threadIdx.x;
    if (blk < NCHUNK) {
        __shared__ int lh[NBUK];
        const int c = blk;
        for (int i = t; i < NBUK; i += 256) lh[i] = 0;
        __syncthreads();
        const int e0 = c * CHUNK;
        const int e1 = min(e0 + CHUNK, N_EDGES);
        const i32x4* p = (const i32x4*)(dst + e0);
        const int n4 = (e1 - e0) >> 2;
        for (int i = t; i < n4; i += 256) {
            i32x4 d = __builtin_nontemporal_load(p + i);
            atomicAdd(&lh[d.x >> 6], 1);
            atomicAdd(&lh[d.y >> 6], 1);
            atomicAdd(&lh[d.z >> 6], 1);
            atomicAdd(&lh[d.w >> 6], 1);
        }
        __syncthreads();
        for (int i = t; i < NBUK; i += 256) {
            int v = lh[i];
            h[(size_t)i * NCHUNK + c] = v;
            if (v) atomicAdd(&tot[i], v);      // fire-and-forget
        }
    } else {
        const int blk2 = blk - NCHUNK;
        if (blk2 < 128) {                      // w1t: 128*256 elems
            int i = blk2 * 256 + t;
            int n = i / IN_F, k = i % IN_F;
            w1t[i] = f2b(W1[(size_t)k * H1_F + n]);
        } else if (blk2 < 160) {               // w2t: 64*128 elems
            int i = (blk2 - 128) * 256 + t;
            int n = i / H1_F, k = i % H1_F;
            w2t[i] = f2b(W2[(size_t)k * H2_F + n]);
        } else {                               // BN folds
            if (t < H1_F) {
                float s = g1[t] * rsqrtf(v1[t] + BN_EPS);
                sc1[t] = s;
                sh1[t] = (b1[t] - m1[t]) * s + be1[t];
            } else if (t < H1_F + H2_F) {
                int f = t - H1_F;
                float s = g2[f] * rsqrtf(v2[f] + BN_EPS);
                sc2[f] = s;
                sh2[f] = (b2[f] - m2[f]) * s + be2[f];
            }
        }
    }
}

// ---------------------------------------------------------------- fused scan: one WAVE per bucket
//   wave b: P(b) = sum_{i<b} tot[i]  (strided accumulate + butterfly),
//   writes boff[b], then rewrites h row b as running chunk offsets
__launch_bounds__(256)
__global__ void scanoffs_kernel(const int* __restrict__ tot, int* __restrict__ boff,
                                int* __restrict__ h, int* __restrict__ rowptr) {
    const int b = (blockIdx.x * blockDim.x + threadIdx.x) >> 6;
    if (b >= NBUK) return;
    const int lane = threadIdx.x & 63;

    int acc = 0;
    for (int i = lane; i < NBUK; i += 64)
        if (i < b) acc += tot[i];
#pragma unroll
    for (int off = 1; off < 64; off <<= 1) acc += __shfl_xor(acc, off);
    // acc == P(b) on every lane
    if (lane == 0) boff[b] = acc;
    if (b == 0 && lane == 0) { boff[NBUK] = N_EDGES; rowptr[N_NODES] = N_EDGES; }

    int run = acc;
    int* row = h + (size_t)b * NCHUNK;
    for (int c0 = 0; c0 < NCHUNK; c0 += 64) {
        int idx = c0 + lane;
        int v = (idx < NCHUNK) ? row[idx] : 0;
        int s = v;
#pragma unroll
        for (int off = 1; off < 64; off <<= 1) {
            int t2 = __shfl_up(s, off);
            if (lane >= off) s += t2;
        }
        if (idx < NCHUNK) row[idx] = run + (s - v);
        run += __shfl(s, 63);
    }
}

// ---------------------------------------------------------------- cscatter: scatter edges to precomputed slots
__launch_bounds__(256)
__global__ void cscatter_kernel(const int* __restrict__ src, const int* __restrict__ dst,
                                const int* __restrict__ h, unsigned* __restrict__ bedges) {
    __shared__ int cur[NBUK];
    const int c = blockIdx.x;
    for (int i = threadIdx.x; i < NBUK; i += 256) cur[i] = h[(size_t)i * NCHUNK + c];
    __syncthreads();
    const int e0 = c * CHUNK;
    const int e1 = min(e0 + CHUNK, N_EDGES);
    const i32x4* pd = (const i32x4*)(dst + e0);
    const i32x4* ps = (const i32x4*)(src + e0);
    const int n4 = (e1 - e0) >> 2;
    for (int i = threadIdx.x; i < n4; i += 256) {
        i32x4 d = __builtin_nontemporal_load(pd + i);
        i32x4 s = __builtin_nontemporal_load(ps + i);
        int slot;
        slot = atomicAdd(&cur[d.x >> 6], 1); bedges[slot] = (unsigned)s.x | ((unsigned)d.x << 16);
        slot = atomicAdd(&cur[d.y >> 6], 1); bedges[slot] = (unsigned)s.y | ((unsigned)d.y << 16);
        slot = atomicAdd(&cur[d.z >> 6], 1); bedges[slot] = (unsigned)s.z | ((unsigned)d.z << 16);
        slot = atomicAdd(&cur[d.w >> 6], 1); bedges[slot] = (unsigned)s.w | ((unsigned)d.w << 16);
    }
}

// ---------------------------------------------------------------- per-bucket CSR build
__launch_bounds__(256)
__global__ void build_kernel(const unsigned* __restrict__ bedges, const int* __restrict__ boff,
                             unsigned short* __restrict__ perm, int* __restrict__ rowptr,
                             float* __restrict__ dinv) {
    __shared__ unsigned e_lds[BCAP];
    __shared__ unsigned short p_lds[BCAP];
    __shared__ int ncnt[64], ncur[64];

    const int b = blockIdx.x;
    const int t = threadIdx.x;
    const int start = boff[b];
    const int end   = boff[b + 1];
    const int cnt   = end - start;
    const bool fits = (cnt <= BCAP);

    if (t < 64) ncnt[t] = 0;
    __syncthreads();

    for (int i = t; i < cnt; i += 256) {
        unsigned e = bedges[start + i];
        if (fits) e_lds[i] = e;
        atomicAdd(&ncnt[(e >> 16) & 63], 1);
    }
    __syncthreads();

    if (t == 0) {
        int a = 0;
        for (int i = 0; i < 64; ++i) { ncur[i] = a; a += ncnt[i]; }
    }
    __syncthreads();

    if (t < 64) {
        int node = b * 64 + t;
        if (node < N_NODES) {
            rowptr[node] = start + ncur[t];
            dinv[node]   = rsqrtf((float)ncnt[t] + 1.0f);   // +1 self loop
        }
    }
    __syncthreads();

    for (int i = t; i < cnt; i += 256) {
        unsigned e = fits ? e_lds[i] : bedges[start + i];
        int slot = atomicAdd(&ncur[(e >> 16) & 63], 1);
        unsigned short s = (unsigned short)(e & 0xFFFFu);
        if (fits) p_lds[slot] = s;
        else      perm[start + slot] = s;
    }
    if (fits) {
        __syncthreads();
        for (int i = t; i < cnt; i += 256) perm[start + i] = p_lds[i];
    }
}

// ---------------------------------------------------------------- MFMA GEMM, row-major bf16 output
template <int KSTEPS, int NTILES, bool A_BF16>
__launch_bounds__(256)
__global__ void mfma_gemm_kernel(const void* __restrict__ Ap, const unsigned short* __restrict__ BT,
                                 const float* __restrict__ dscale, unsigned short* __restrict__ C,
                                 int M) {
    constexpr int K  = KSTEPS * 32;
    constexpr int NF = NTILES * 16;
    const int wave = threadIdx.x >> 6;
    const int lane = threadIdx.x & 63;
    const int r0   = (blockIdx.x * 4 + wave) * 16;
    const int m    = lane & 15;
    const int kb   = lane >> 4;

    int arow = r0 + m;
    if (arow >= M) arow = M - 1;

    f32x4 acc[NTILES];
#pragma unroll
    for (int nt = 0; nt < NTILES; ++nt) acc[nt] = (f32x4)(0.f);

#pragma unroll
    for (int ks = 0; ks < KSTEPS; ++ks) {
        const int k0 = ks * 32 + kb * 8;
        bf16x8 a;
        if constexpr (A_BF16) {
            a = *(const bf16x8*)((const unsigned short*)Ap + (size_t)arow * K + k0);
        } else {
            const float* af = (const float*)Ap + (size_t)arow * K + k0;
            f32x4 lo = __builtin_nontemporal_load((const f32x4*)af);
            f32x4 hi = __builtin_nontemporal_load((const f32x4*)(af + 4));
            union { bf16x8 v; unsigned short u[8]; } pk;
            pk.u[0] = f2b(lo.x); pk.u[1] = f2b(lo.y); pk.u[2] = f2b(lo.z); pk.u[3] = f2b(lo.w);
            pk.u[4] = f2b(hi.x); pk.u[5] = f2b(hi.y); pk.u[6] = f2b(hi.z); pk.u[7] = f2b(hi.w);
            a = pk.v;
        }
#pragma unroll
        for (int nt = 0; nt < NTILES; ++nt) {
            bf16x8 b = *(const bf16x8*)(BT + (size_t)(nt * 16 + m) * K + k0);
            acc[nt] = __builtin_amdgcn_mfma_f32_16x16x32_bf16(a, b, acc[nt], 0, 0, 0);
        }
    }

#pragma unroll
    for (int reg = 0; reg < 4; ++reg) {
        const int r = r0 + kb * 4 + reg;
        if (r < M) {
            const float ds = dscale[r];
#pragma unroll
            for (int nt = 0; nt < NTILES; ++nt)
                C[(size_t)r * NF + nt * 16 + m] = f2b(acc[nt][reg] * ds);
        }
    }
}

// ---------------------------------------------------------------- fused aggregation (round-11 proven: VGPR 40, 52% occ)
template <int HF, bool FINAL>
__launch_bounds__(256)
__global__ void agg_kernel(const int* __restrict__ rowptr, const unsigned short* __restrict__ perm,
                           const unsigned short* __restrict__ xw, const float* __restrict__ dinv,
                           const float* __restrict__ sc, const float* __restrict__ sh,
                           const float* __restrict__ Wl, const float* __restrict__ bl,
                           void* __restrict__ outp) {
    constexpr int LPE = HF / 8;
    constexpr int G   = 64 / LPE;
    const int wave = threadIdx.x >> 6;
    const int node = blockIdx.x * 4 + wave;
    if (node >= N_NODES) return;
    const int lane = threadIdx.x & 63;
    const int grp  = lane / LPE;
    const int fl   = (lane % LPE) * 8;

    float aA[8];
#pragma unroll
    for (int i = 0; i < 8; ++i) aA[i] = 0.f;

    if (grp == 0) {
        u32x4 u = *(const u32x4*)(xw + (size_t)node * HF + fl);
#pragma unroll
        for (int i = 0; i < 4; ++i) add2(aA[2 * i], aA[2 * i + 1], u[i]);
    }

    const int start = rowptr[node];
    const int end   = rowptr[node + 1];
    for (int base = start; base < end; base += 64) {
        int pidx = base + lane;
        int pv = (int)__builtin_nontemporal_load(perm + (pidx < end ? pidx : end - 1));
        int ne = end - base;
        if (ne > 64) ne = 64;
        if (ne == 64) {
#pragma unroll
            for (int j = 0; j < 64; j += G) {
                int s = __shfl(pv, j + grp);
                u32x4 u = *(const u32x4*)(xw + (size_t)s * HF + fl);
#pragma unroll
                for (int i = 0; i < 4; ++i) add2(aA[2 * i], aA[2 * i + 1], u[i]);
            }
        } else {
            for (int j = 0; j < ne; j += G) {
                int s = __shfl(pv, j + grp);
                if (j + grp < ne) {
                    u32x4 u = *(const u32x4*)(xw + (size_t)s * HF + fl);
#pragma unroll
                    for (int i = 0; i < 4; ++i) add2(aA[2 * i], aA[2 * i + 1], u[i]);
                }
            }
        }
    }

#pragma unroll
    for (int off = LPE; off < 64; off <<= 1)
#pragma unroll
        for (int i = 0; i < 8; ++i) aA[i] += __shfl_xor(aA[i], off);

    const float dv = dinv[node];
    f32x4 scl = *(const f32x4*)(sc + fl);
    f32x4 sch = *(const f32x4*)(sc + fl + 4);
    f32x4 shl = *(const f32x4*)(sh + fl);
    f32x4 shh = *(const f32x4*)(sh + fl + 4);
    float y[8];
#pragma unroll
    for (int i = 0; i < 4; ++i) {
        y[i]     = fmaxf(aA[i] * (dv * scl[i]) + shl[i], 0.f);
        y[i + 4] = fmaxf(aA[i + 4] * (dv * sch[i]) + shh[i], 0.f);
    }

    if constexpr (!FINAL) {
        if (lane < LPE) {
            u32x4 o;
#pragma unroll
            for (int i = 0; i < 4; ++i)
                o[i] = (unsigned)f2b(y[2 * i]) | ((unsigned)f2b(y[2 * i + 1]) << 16);
            __builtin_nontemporal_store(o, (u32x4*)((unsigned short*)outp + (size_t)node * HF + fl));
        }
    } else {
        float p0 = 0.f, p1 = 0.f;
#pragma unroll
        for (int i = 0; i < 8; ++i) {
            p0 += y[i] * Wl[(fl + i) * 2 + 0];
            p1 += y[i] * Wl[(fl + i) * 2 + 1];
        }
#pragma unroll
        for (int off = 1; off < LPE; off <<= 1) {
            p0 += __shfl_xor(p0, off);
            p1 += __shfl_xor(p1, off);
        }
        if (lane == 0) {
            float* o = (float*)outp;
            o[(size_t)node * 2 + 0] = p0 + bl[0];
            o[(size_t)node * 2 + 1] = p1 + bl[1];
        }
    }
}

// ---------------------------------------------------------------- launcher
extern "C" void kernel_launch(void* const* d_in, const int* in_sizes, int n_in,
                              void* d_out, int out_size, void* d_ws, size_t ws_size,
                              hipStream_t stream) {
    const float* x   = (const float*)d_in[0];
    const int*   ei  = (const int*)d_in[1];
    const float* W1  = (const float*)d_in[2];
    const float* b1  = (const float*)d_in[3];
    const float* g1  = (const float*)d_in[4];
    const float* be1 = (const float*)d_in[5];
    const float* m1  = (const float*)d_in[6];
    const float* v1  = (const float*)d_in[7];
    const float* W2  = (const float*)d_in[8];
    const float* b2  = (const float*)d_in[9];
    const float* g2  = (const float*)d_in[10];
    const float* be2 = (const float*)d_in[11];
    const float* m2  = (const float*)d_in[12];
    const float* v2  = (const float*)d_in[13];
    const float* Wl  = (const float*)d_in[14];
    const float* bl  = (const float*)d_in[15];

    const int* src = ei;            // edge_index[0]
    const int* dst = ei + N_EDGES;  // edge_index[1]

    // workspace layout (4B units)
    int*            h      = (int*)d_ws;                          // NBUK*NCHUNK (bucket-major)
    int*            tot    = h + (size_t)NBUK * NCHUNK;           // 1024
    int*            boff   = tot + 1024;                          // 1024
    int*            rowptr = boff + 1024;                         // 50016
    float*          dinv   = (float*)(rowptr + 50016);            // 50016
    float*          sc1    = dinv + 50016;                        // 128
    float*          sh1    = sc1 + 128;                           // 128
    float*          sc2    = sh1 + 128;                           // 64
    float*          sh2    = sc2 + 64;                            // 64
    unsigned*       bedges = (unsigned*)(sh2 + 64);               // E
    unsigned short* perm   = (unsigned short*)(bedges + N_EDGES); // E ushorts
    unsigned short* xwb    = perm + N_EDGES;                      // N*128 bf16 (row-major)
    unsigned short* h1b    = xwb + (size_t)N_NODES * H1_F;        // N*128 bf16 (row-major)
    unsigned short* w1t    = h1b + (size_t)N_NODES * H1_F;        // 128*256 bf16
    unsigned short* w2t    = w1t + H1_F * IN_F;                   // 64*128 bf16

    hipMemsetAsync(tot, 0, 1024 * sizeof(int), stream);

    // ---- CSR build + prep (chain compressed to 4 kernels) ----
    chist_prep_kernel<<<NCHUNK + 161, 256, 0, stream>>>(dst, h, tot,
                                                        W1, W2, w1t, w2t,
                                                        g1, be1, m1, v1, b1,
                                                        g2, be2, m2, v2, b2,
                                                        sc1, sh1, sc2, sh2);
    scanoffs_kernel<<<(NBUK * 64 + 255) / 256, 256, 0, stream>>>(tot, boff, h, rowptr);
    cscatter_kernel<<<NCHUNK, 256, 0, stream>>>(src, dst, h, bedges);
    build_kernel<<<NBUK, 256, 0, stream>>>(bedges, boff, perm, rowptr, dinv);

    // ---- layer 1 ----
    mfma_gemm_kernel<IN_F / 32, H1_F / 16, false><<<(N_NODES + 63) / 64, 256, 0, stream>>>(
        x, w1t, dinv, xwb, N_NODES);
    agg_kernel<H1_F, false><<<(N_NODES + 3) / 4, 256, 0, stream>>>(
        rowptr, perm, xwb, dinv, sc1, sh1, nullptr, nullptr, h1b);

    // ---- layer 2 + fused final linear ----
    mfma_gemm_kernel<H1_F / 32, H2_F / 16, true><<<(N_NODES + 63) / 64, 256, 0, stream>>>(
        h1b, w2t, dinv, xwb, N_NODES);
    agg_kernel<H2_F, true><<<(N_NODES + 3) / 4, 256, 0, stream>>>(
        rowptr, perm, xwb, dinv, sc2, sh2, Wl, bl, (float*)d_out);
}